// Round 1
// baseline (430.246 us; speedup 1.0000x reference)
//
#include <hip/hip_runtime.h>

// FS-Swish 16-step spiking-threshold accumulation.
// out = sum_t z_t * d[t], v_{t+1} = v_t - z_t * h[t], z_t = (v_t > T[t]).
// Constants are fixed in the reference; hardcode them so they fold into
// SGPR immediates instead of per-thread loads.

__device__ __constant__ // not needed, but keep constants in one place
static const float kH[16] = {0.4462f, 0.9426f, 0.5828f, 0.2679f, 0.1929f, 1.1032f, 0.0062f, 1.7608f,
                             1.6892f, 1.0465f, 2.2203f, -0.0518f, 0.9965f, 1.2357f, 0.7535f, 1.3039f};
__device__ __constant__
static const float kD[16] = {0.1441f, 1.0263f, 0.5819f, 0.2583f, 0.089f, 0.8074f, 0.1049f, 1.2033f,
                             1.8082f, 0.4312f, 2.2586f, -0.2693f, 0.8391f, 0.0463f, 0.2339f, 0.1115f};
__device__ __constant__
static const float kT[16] = {-0.4326f, 0.7987f, 0.1965f, -0.0293f, 1.7898f, 0.4043f, -0.1738f, -0.0356f,
                             2.1835f, -0.0467f, 2.3067f, -1.7284f, 1.281f, 0.942f, -0.245f, -0.5279f};

__device__ __forceinline__ void fs_step(float& v, float& o, float h, float d, float T) {
    // (v - T > 0) == (v > T) exactly in IEEE fp32.
    float m = (v > T) ? 1.0f : 0.0f;
    v = fmaf(m, -h, v);
    o = fmaf(m, d, o);
}

__global__ __launch_bounds__(256) void fs_swish_vec4(const float4* __restrict__ x,
                                                     float4* __restrict__ out, int n4) {
    int i = blockIdx.x * blockDim.x + threadIdx.x;
    if (i >= n4) return;
    float4 v = x[i];
    float4 o = make_float4(0.f, 0.f, 0.f, 0.f);
#pragma unroll
    for (int t = 0; t < 16; ++t) {
        const float h = kH[t], d = kD[t], T = kT[t];
        fs_step(v.x, o.x, h, d, T);
        fs_step(v.y, o.y, h, d, T);
        fs_step(v.z, o.z, h, d, T);
        fs_step(v.w, o.w, h, d, T);
    }
    out[i] = o;
}

__global__ __launch_bounds__(256) void fs_swish_tail(const float* __restrict__ x,
                                                     float* __restrict__ out,
                                                     int start, int n) {
    int i = start + blockIdx.x * blockDim.x + threadIdx.x;
    if (i >= n) return;
    float v = x[i];
    float o = 0.f;
#pragma unroll
    for (int t = 0; t < 16; ++t) fs_step(v, o, kH[t], kD[t], kT[t]);
    out[i] = o;
}

extern "C" void kernel_launch(void* const* d_in, const int* in_sizes, int n_in,
                              void* d_out, int out_size, void* d_ws, size_t ws_size,
                              hipStream_t stream) {
    const float* x = (const float*)d_in[0];
    float* out = (float*)d_out;
    const int n = in_sizes[0];           // 64*256*64*64 = 67108864
    const int n4 = n >> 2;

    if (n4 > 0) {
        const int block = 256;
        const int grid = (n4 + block - 1) / block;   // 65536 blocks
        fs_swish_vec4<<<grid, block, 0, stream>>>((const float4*)x, (float4*)out, n4);
    }
    const int tail_start = n4 << 2;
    if (tail_start < n) {
        const int rem = n - tail_start;
        fs_swish_tail<<<(rem + 255) / 256, 256, 0, stream>>>(x, out, tail_start, n);
    }
}

// Round 4
// 429.611 us; speedup vs baseline: 1.0015x; 1.0015x over previous
//
#include <hip/hip_runtime.h>

// FS-Swish 16-step spiking-threshold accumulation.
// out = sum_t z_t * d[t], v_{t+1} = v_t - z_t * h[t], z_t = (v_t > T[t]).
// Pure streaming kernel: 268 MB read + 268 MB write, zero reuse.
// Working set (536 MB) is 2x the 256 MiB L3 -> use non-temporal load/store
// to bypass cache allocation. NB: __builtin_nontemporal_* rejects
// HIP_vector_type (a class); use a native clang ext_vector_type. Vector
// elements can't bind to float& -> unpack to scalars inside fs_apply4.

typedef float v4f __attribute__((ext_vector_type(4)));

static const __device__ float kH[16] = {0.4462f, 0.9426f, 0.5828f, 0.2679f, 0.1929f, 1.1032f, 0.0062f, 1.7608f,
                                        1.6892f, 1.0465f, 2.2203f, -0.0518f, 0.9965f, 1.2357f, 0.7535f, 1.3039f};
static const __device__ float kD[16] = {0.1441f, 1.0263f, 0.5819f, 0.2583f, 0.089f, 0.8074f, 0.1049f, 1.2033f,
                                        1.8082f, 0.4312f, 2.2586f, -0.2693f, 0.8391f, 0.0463f, 0.2339f, 0.1115f};
static const __device__ float kT[16] = {-0.4326f, 0.7987f, 0.1965f, -0.0293f, 1.7898f, 0.4043f, -0.1738f, -0.0356f,
                                        2.1835f, -0.0467f, 2.3067f, -1.7284f, 1.281f, 0.942f, -0.245f, -0.5279f};

__device__ __forceinline__ void fs_step(float& v, float& o, float h, float d, float T) {
    // (v - T > 0) == (v > T) exactly in IEEE fp32.
    float m = (v > T) ? 1.0f : 0.0f;
    v = fmaf(m, -h, v);
    o = fmaf(m, d, o);
}

__device__ __forceinline__ v4f fs_apply4(v4f vin) {
    float v0 = vin.x, v1 = vin.y, v2 = vin.z, v3 = vin.w;
    float o0 = 0.f, o1 = 0.f, o2 = 0.f, o3 = 0.f;
#pragma unroll
    for (int t = 0; t < 16; ++t) {
        const float h = kH[t], d = kD[t], T = kT[t];
        fs_step(v0, o0, h, d, T);
        fs_step(v1, o1, h, d, T);
        fs_step(v2, o2, h, d, T);
        fs_step(v3, o3, h, d, T);
    }
    v4f o = {o0, o1, o2, o3};
    return o;
}

// Each thread handles 2 v4fs (32 B) per grid-stride iteration; both loads
// are issued before either result is consumed (ILP for latency hiding).
__global__ __launch_bounds__(256) void fs_swish_vec4x2(const v4f* __restrict__ x,
                                                       v4f* __restrict__ out, int n4) {
    const int stride = gridDim.x * blockDim.x;
    int i = blockIdx.x * blockDim.x + threadIdx.x;
    for (; i + stride < n4; i += 2 * stride) {
        v4f a = __builtin_nontemporal_load(&x[i]);
        v4f b = __builtin_nontemporal_load(&x[i + stride]);
        v4f oa = fs_apply4(a);
        v4f ob = fs_apply4(b);
        __builtin_nontemporal_store(oa, &out[i]);
        __builtin_nontemporal_store(ob, &out[i + stride]);
    }
    if (i < n4) {
        v4f a = __builtin_nontemporal_load(&x[i]);
        __builtin_nontemporal_store(fs_apply4(a), &out[i]);
    }
}

__global__ __launch_bounds__(256) void fs_swish_tail(const float* __restrict__ x,
                                                     float* __restrict__ out,
                                                     int start, int n) {
    int i = start + blockIdx.x * blockDim.x + threadIdx.x;
    if (i >= n) return;
    float v = x[i];
    float o = 0.f;
#pragma unroll
    for (int t = 0; t < 16; ++t) fs_step(v, o, kH[t], kD[t], kT[t]);
    out[i] = o;
}

extern "C" void kernel_launch(void* const* d_in, const int* in_sizes, int n_in,
                              void* d_out, int out_size, void* d_ws, size_t ws_size,
                              hipStream_t stream) {
    const float* x = (const float*)d_in[0];
    float* out = (float*)d_out;
    const int n = in_sizes[0];           // 64*256*64*64 = 67108864
    const int n4 = n >> 2;               // 16777216 float4s

    if (n4 > 0) {
        const int block = 256;
        // 2 float4/thread/iteration: grid covers n4 in one stride pair.
        const int grid = (n4 + block * 2 - 1) / (block * 2);   // 32768 blocks
        fs_swish_vec4x2<<<grid, block, 0, stream>>>((const v4f*)x, (v4f*)out, n4);
    }
    const int tail_start = n4 << 2;
    if (tail_start < n) {
        const int rem = n - tail_start;
        fs_swish_tail<<<(rem + 255) / 256, 256, 0, stream>>>(x, out, tail_start, n);
    }
}